// Round 6
// baseline (188.380 us; speedup 1.0000x reference)
//
#include <hip/hip_runtime.h>

// ---------------------------------------------------------------------------
// GCN 2-layer: out = A_norm * relu(A_norm*(X@W1)+b1) @ W2 + b2
// A_norm = D^-1/2 (A + I) D^-1/2.
//
// Round-6: channel-SLICED gathers (32-ch slices -> 3.2 MB tables, L2-resident
// per XCD), slice-major intermediate layouts, atomic-offset CSR bucket sort
// (1 tiny scan instead of 3-kernel 38k-entry scan), fused weight-prep.
//   hs  = bf16( dinv * (X@W1) )   slice-major [4][n][32]    [gemm1, MFMA]
//   h1  = relu(dinv*(A.hs)+b1)    slice-major [4][n][32]    [gather1s x4]
//   ps2 = bf16( dinv * (h1@W2) )  slice-major [2][n][32]    [gemm2, MFMA]
//   out = dinv*(A.ps2)+b2  fp32   row-major [n][64]         [gather2s x2]
// ---------------------------------------------------------------------------

typedef float f32x4 __attribute__((ext_vector_type(4)));
typedef short bf16x8 __attribute__((ext_vector_type(8)));

#define EPB 4096   // edges per block in bucket pass 1

__device__ inline float bf2f(unsigned short u) {
    return __uint_as_float(((unsigned int)u) << 16);
}
__device__ inline unsigned short f2bf(float f) {
    unsigned int x = __float_as_uint(f);
    x = x + 0x7FFFu + ((x >> 16) & 1u);   // round-to-nearest-even
    return (unsigned short)(x >> 16);
}

__global__ __launch_bounds__(256) void k_init(int* __restrict__ bucket_cnt) {
    bucket_cnt[threadIdx.x] = 0;
}

// Pass 1: per-(bucket,block) offsets via atomicAdd into bucket counters.
// Extra blocks (>= nbR) convert/transpose weights to bf16.
__global__ __launch_bounds__(256) void k_rhist(const int* __restrict__ col,
                                               int* __restrict__ bbase,
                                               int* __restrict__ bucket_cnt,
                                               const float* __restrict__ W1,
                                               const float* __restrict__ W2,
                                               unsigned short* __restrict__ Wt1,
                                               unsigned short* __restrict__ Wt2,
                                               int e, int nbR, int nbB) {
    if ((int)blockIdx.x >= nbR) {
        int i = ((int)blockIdx.x - nbR) * 256 + threadIdx.x;
        if (i < 16384) {                       // W1: 128x128
            int k = i >> 7, nc = i & 127;
            Wt1[nc * 128 + k] = f2bf(W1[i]);
        } else if (i < 24576) {                // W2: 128x64
            int i2 = i - 16384;
            int k = i2 >> 6, nc = i2 & 63;
            Wt2[nc * 128 + k] = f2bf(W2[i2]);
        }
        return;
    }
    __shared__ int h[256];
    int t = threadIdx.x;
    h[t] = 0;
    __syncthreads();
    int base = blockIdx.x * EPB;
#pragma unroll
    for (int i = 0; i < EPB / 256; ++i) {
        int idx = base + t + i * 256;
        if (idx < e) atomicAdd(&h[col[idx] >> 8], 1);
    }
    __syncthreads();
    if (t < nbB) bbase[t * nbR + blockIdx.x] = atomicAdd(&bucket_cnt[t], h[t]);
}

// Tiny single-block exclusive scan of the 196 bucket counts.
__global__ __launch_bounds__(256) void k_scanB(const int* __restrict__ bucket_cnt,
                                               int* __restrict__ bucket_base, int nbB) {
    __shared__ int s[256];
    int t = threadIdx.x;
    int v = (t < nbB) ? bucket_cnt[t] : 0;
    s[t] = v;
    __syncthreads();
#pragma unroll
    for (int off = 1; off < 256; off <<= 1) {
        int u = (t >= off) ? s[t - off] : 0;
        __syncthreads();
        s[t] += u;
        __syncthreads();
    }
    if (t < nbB) bucket_base[t] = s[t] - v;
    if (t == 255) bucket_base[nbB] = s[255];
}

// Pass 1 scatter into bucket-grouped tmp (block-owned runs).
__global__ __launch_bounds__(256) void k_rscatter(const int* __restrict__ row,
                                                  const int* __restrict__ col,
                                                  const int* __restrict__ bucket_base,
                                                  const int* __restrict__ bbase,
                                                  unsigned int* __restrict__ tmp,
                                                  int e, int nbR, int nbB) {
    __shared__ int base[256];
    __shared__ int h[256];
    int t = threadIdx.x;
    base[t] = (t < nbB) ? bucket_base[t] + bbase[t * nbR + blockIdx.x] : 0;
    h[t] = 0;
    __syncthreads();
    int b0 = blockIdx.x * EPB;
#pragma unroll
    for (int i = 0; i < EPB / 256; ++i) {
        int idx = b0 + t + i * 256;
        if (idx < e) {
            int c = col[idx];
            int bin = c >> 8;
            int rk = atomicAdd(&h[bin], 1);
            tmp[base[bin] + rk] =
                ((unsigned int)(c & 255) << 16) | (unsigned int)row[idx];
        }
    }
}

// Pass 2: per-bucket counting sort; emits indptr, dinv, srcidx.
__global__ __launch_bounds__(256) void k_bsort(const unsigned int* __restrict__ tmp,
                                               const int* __restrict__ bucket_base,
                                               int* __restrict__ indptr,
                                               float* __restrict__ dinv,
                                               unsigned short* __restrict__ srcidx,
                                               int n, int e, int nbB) {
    __shared__ int cnt[256];
    __shared__ int pre[256];
    int b = blockIdx.x;
    int t = threadIdx.x;
    int beg = bucket_base[b];
    int end = bucket_base[b + 1];

    cnt[t] = 0;
    __syncthreads();
    for (int i = beg + t; i < end; i += 256) atomicAdd(&cnt[tmp[i] >> 16], 1);
    __syncthreads();
    int v = cnt[t];
    pre[t] = v;
    __syncthreads();
#pragma unroll
    for (int off = 1; off < 256; off <<= 1) {
        int u = (t >= off) ? pre[t - off] : 0;
        __syncthreads();
        pre[t] += u;
        __syncthreads();
    }
    int myexcl = pre[t] - v;
    int node = b * 256 + t;
    if (node < n) {
        indptr[node] = beg + myexcl;
        dinv[node] = rsqrtf((float)v + 1.0f);
    }
    if (b == nbB - 1 && t == 0) indptr[n] = e;
    __syncthreads();
    pre[t] = beg + myexcl;
    cnt[t] = 0;
    __syncthreads();
    for (int i = beg + t; i < end; i += 256) {
        unsigned int u = tmp[i];
        int cl = u >> 16;
        int rk = atomicAdd(&cnt[cl], 1);
        srcidx[pre[cl] + rk] = (unsigned short)(u & 0xFFFFu);
    }
}

// GEMM1 (MFMA): hs = bf16( dinv[i]*(X@W1) ), slice-major [4][n][32].
__global__ __launch_bounds__(256, 2) void k_gemm1(const float* __restrict__ x,
                                                  const unsigned short* __restrict__ Wt,
                                                  const float* __restrict__ dinv,
                                                  unsigned short* __restrict__ hs, int n) {
    __shared__ unsigned short Xs[128 * 136];
    __shared__ unsigned short Ws[128 * 136];
    __shared__ float dinv_s[128];
    int t = threadIdx.x;
    int r0blk = blockIdx.x * 128;

#pragma unroll
    for (int i = 0; i < 8; ++i) {
        int c = t + i * 256;
        int nc = c >> 4;
        int k0 = (c & 15) * 8;
        bf16x8 v = *(const bf16x8*)&Wt[nc * 128 + k0];
        *(bf16x8*)&Ws[nc * 136 + k0] = v;
    }
#pragma unroll
    for (int i = 0; i < 16; ++i) {
        int c = t + i * 256;
        int r = c >> 5;
        int kq = c & 31;
        float4 v = make_float4(0.f, 0.f, 0.f, 0.f);
        int gr = r0blk + r;
        if (gr < n) v = ((const float4*)x)[gr * 32 + kq];
        ushort4 o;
        o.x = f2bf(v.x); o.y = f2bf(v.y); o.z = f2bf(v.z); o.w = f2bf(v.w);
        *(ushort4*)&Xs[r * 136 + kq * 4] = o;
    }
    if (t < 128) {
        int gr = r0blk + t;
        dinv_s[t] = (gr < n) ? dinv[gr] : 0.f;
    }
    __syncthreads();

    int lane = t & 63, wave = t >> 6;
    int lrow = lane & 15;
    int lk = (lane >> 4) * 8;

    f32x4 acc[2][8];
#pragma unroll
    for (int mi = 0; mi < 2; ++mi)
#pragma unroll
        for (int ni = 0; ni < 8; ++ni) acc[mi][ni] = (f32x4){0.f, 0.f, 0.f, 0.f};

#pragma unroll
    for (int ks = 0; ks < 4; ++ks) {
        int kk = ks * 32 + lk;
        bf16x8 a0 = *(bf16x8*)&Xs[(wave * 32 + lrow) * 136 + kk];
        bf16x8 a1 = *(bf16x8*)&Xs[(wave * 32 + 16 + lrow) * 136 + kk];
#pragma unroll
        for (int ni = 0; ni < 8; ++ni) {
            bf16x8 b = *(bf16x8*)&Ws[(ni * 16 + lrow) * 136 + kk];
            acc[0][ni] = __builtin_amdgcn_mfma_f32_16x16x32_bf16(a0, b, acc[0][ni], 0, 0, 0);
            acc[1][ni] = __builtin_amdgcn_mfma_f32_16x16x32_bf16(a1, b, acc[1][ni], 0, 0, 0);
        }
    }

    int rq = (lane >> 4) * 4;
    size_t ns32 = (size_t)n * 32;
#pragma unroll
    for (int mi = 0; mi < 2; ++mi)
#pragma unroll
        for (int r = 0; r < 4; ++r) {
            int lrw = wave * 32 + mi * 16 + rq + r;
            int grow = r0blk + lrw;
            if (grow < n) {
                float dv = dinv_s[lrw];
#pragma unroll
                for (int ni = 0; ni < 8; ++ni)
                    hs[(size_t)(ni >> 1) * ns32 + (size_t)grow * 32 + (ni & 1) * 16 + lrow] =
                        f2bf(acc[mi][ni][r] * dv);
            }
        }
}

// Gather1 sliced: grid = 4 slices x ceil(n/4) blocks; wave per (node,slice).
// Quarter-wave per edge: 16 lanes x uint (2ch) = 64 B = one slice row.
__global__ __launch_bounds__(256) void k_gather1s(const int* __restrict__ indptr,
                                                  const unsigned short* __restrict__ srcidx,
                                                  const unsigned short* __restrict__ hs,
                                                  const float* __restrict__ dinv,
                                                  const float* __restrict__ b1,
                                                  unsigned short* __restrict__ h1,
                                                  int n, int nbn) {
    int s = blockIdx.x / nbn;
    int node = (blockIdx.x % nbn) * 4 + (threadIdx.x >> 6);
    if (node >= n) return;
    int lane = threadIdx.x & 63;
    int es = lane >> 4, cp = lane & 15;
    const unsigned int* hv = (const unsigned int*)(hs + (size_t)s * n * 32);

    int beg = indptr[node], end = indptr[node + 1];
    float2 a0 = make_float2(0.f, 0.f), a1 = a0;
    int j = beg;
    for (; j + 7 < end; j += 8) {
        int s0 = srcidx[j + es];
        int s1 = srcidx[j + 4 + es];
        unsigned int u0 = hv[s0 * 16 + cp];
        unsigned int u1 = hv[s1 * 16 + cp];
        a0.x += bf2f((unsigned short)u0); a0.y += bf2f((unsigned short)(u0 >> 16));
        a1.x += bf2f((unsigned short)u1); a1.y += bf2f((unsigned short)(u1 >> 16));
    }
    if (j + 3 < end) {
        unsigned int u = hv[srcidx[j + es] * 16 + cp];
        a0.x += bf2f((unsigned short)u); a0.y += bf2f((unsigned short)(u >> 16));
        j += 4;
    }
    if (j + es < end) {
        unsigned int u = hv[srcidx[j + es] * 16 + cp];
        a1.x += bf2f((unsigned short)u); a1.y += bf2f((unsigned short)(u >> 16));
    }
    if (es == 0) {   // self-loop
        unsigned int u = hv[node * 16 + cp];
        a0.x += bf2f((unsigned short)u); a0.y += bf2f((unsigned short)(u >> 16));
    }
    float2 t2;
    t2.x = a0.x + a1.x;
    t2.y = a0.y + a1.y;
    t2.x += __shfl_xor(t2.x, 16); t2.x += __shfl_xor(t2.x, 32);
    t2.y += __shfl_xor(t2.y, 16); t2.y += __shfl_xor(t2.y, 32);

    if (lane < 16) {
        float d = dinv[node];
        float2 bb = *(const float2*)&b1[s * 32 + cp * 2];
        unsigned int o = ((unsigned int)f2bf(fmaxf(t2.y * d + bb.y, 0.f)) << 16) |
                         (unsigned int)f2bf(fmaxf(t2.x * d + bb.x, 0.f));
        ((unsigned int*)h1)[(size_t)s * n * 16 + (size_t)node * 16 + cp] = o;
    }
}

// GEMM2 (MFMA): ps2 = bf16( dinv[i]*(h1@W2) ). h1 slice-major [4][n][32];
// ps2 slice-major [2][n][32].
__global__ __launch_bounds__(256, 3) void k_gemm2(const unsigned short* __restrict__ h1,
                                                  const unsigned short* __restrict__ Wt,
                                                  const float* __restrict__ dinv,
                                                  unsigned short* __restrict__ ps2, int n) {
    __shared__ unsigned short Xs[128 * 136];
    __shared__ unsigned short Ws[64 * 136];
    __shared__ float dinv_s[128];
    int t = threadIdx.x;
    int r0blk = blockIdx.x * 128;
    size_t ns32 = (size_t)n * 32;

#pragma unroll
    for (int i = 0; i < 4; ++i) {
        int c = t + i * 256;
        int nc = c >> 4;
        int k0 = (c & 15) * 8;
        bf16x8 v = *(const bf16x8*)&Wt[nc * 128 + k0];
        *(bf16x8*)&Ws[nc * 136 + k0] = v;
    }
#pragma unroll
    for (int i = 0; i < 8; ++i) {
        int c = t + i * 256;
        int r = c >> 4;
        int k0 = (c & 15) * 8;
        int gr = r0blk + r;
        bf16x8 v = (bf16x8)(short)0;
        if (gr < n) v = *(const bf16x8*)&h1[(size_t)(k0 >> 5) * ns32 + (size_t)gr * 32 + (k0 & 31)];
        *(bf16x8*)&Xs[r * 136 + k0] = v;
    }
    if (t < 128) {
        int gr = r0blk + t;
        dinv_s[t] = (gr < n) ? dinv[gr] : 0.f;
    }
    __syncthreads();

    int lane = t & 63, wave = t >> 6;
    int lrow = lane & 15;
    int lk = (lane >> 4) * 8;

    f32x4 acc[2][4];
#pragma unroll
    for (int mi = 0; mi < 2; ++mi)
#pragma unroll
        for (int ni = 0; ni < 4; ++ni) acc[mi][ni] = (f32x4){0.f, 0.f, 0.f, 0.f};

#pragma unroll
    for (int ks = 0; ks < 4; ++ks) {
        int kk = ks * 32 + lk;
        bf16x8 a0 = *(bf16x8*)&Xs[(wave * 32 + lrow) * 136 + kk];
        bf16x8 a1 = *(bf16x8*)&Xs[(wave * 32 + 16 + lrow) * 136 + kk];
#pragma unroll
        for (int ni = 0; ni < 4; ++ni) {
            bf16x8 b = *(bf16x8*)&Ws[(ni * 16 + lrow) * 136 + kk];
            acc[0][ni] = __builtin_amdgcn_mfma_f32_16x16x32_bf16(a0, b, acc[0][ni], 0, 0, 0);
            acc[1][ni] = __builtin_amdgcn_mfma_f32_16x16x32_bf16(a1, b, acc[1][ni], 0, 0, 0);
        }
    }

    int rq = (lane >> 4) * 4;
#pragma unroll
    for (int mi = 0; mi < 2; ++mi)
#pragma unroll
        for (int r = 0; r < 4; ++r) {
            int lrw = wave * 32 + mi * 16 + rq + r;
            int grow = r0blk + lrw;
            if (grow < n) {
                float dv = dinv_s[lrw];
#pragma unroll
                for (int ni = 0; ni < 4; ++ni)
                    ps2[(size_t)(ni >> 1) * ns32 + (size_t)grow * 32 + (ni & 1) * 16 + lrow] =
                        f2bf(acc[mi][ni][r] * dv);
            }
        }
}

// Gather2 sliced: 2 slices of 32 ch; fp32 output row-major [n][64].
__global__ __launch_bounds__(256) void k_gather2s(const int* __restrict__ indptr,
                                                  const unsigned short* __restrict__ srcidx,
                                                  const unsigned short* __restrict__ ps2,
                                                  const float* __restrict__ dinv,
                                                  const float* __restrict__ b2,
                                                  float* __restrict__ out,
                                                  int n, int nbn) {
    int s = blockIdx.x / nbn;
    int node = (blockIdx.x % nbn) * 4 + (threadIdx.x >> 6);
    if (node >= n) return;
    int lane = threadIdx.x & 63;
    int es = lane >> 4, cp = lane & 15;
    const unsigned int* pv = (const unsigned int*)(ps2 + (size_t)s * n * 32);

    int beg = indptr[node], end = indptr[node + 1];
    float2 a0 = make_float2(0.f, 0.f), a1 = a0;
    int j = beg;
    for (; j + 7 < end; j += 8) {
        int s0 = srcidx[j + es];
        int s1 = srcidx[j + 4 + es];
        unsigned int u0 = pv[s0 * 16 + cp];
        unsigned int u1 = pv[s1 * 16 + cp];
        a0.x += bf2f((unsigned short)u0); a0.y += bf2f((unsigned short)(u0 >> 16));
        a1.x += bf2f((unsigned short)u1); a1.y += bf2f((unsigned short)(u1 >> 16));
    }
    if (j + 3 < end) {
        unsigned int u = pv[srcidx[j + es] * 16 + cp];
        a0.x += bf2f((unsigned short)u); a0.y += bf2f((unsigned short)(u >> 16));
        j += 4;
    }
    if (j + es < end) {
        unsigned int u = pv[srcidx[j + es] * 16 + cp];
        a1.x += bf2f((unsigned short)u); a1.y += bf2f((unsigned short)(u >> 16));
    }
    if (es == 0) {   // self-loop
        unsigned int u = pv[node * 16 + cp];
        a0.x += bf2f((unsigned short)u); a0.y += bf2f((unsigned short)(u >> 16));
    }
    float2 t2;
    t2.x = a0.x + a1.x;
    t2.y = a0.y + a1.y;
    t2.x += __shfl_xor(t2.x, 16); t2.x += __shfl_xor(t2.x, 32);
    t2.y += __shfl_xor(t2.y, 16); t2.y += __shfl_xor(t2.y, 32);

    if (lane < 16) {
        float d = dinv[node];
        float2 bb = *(const float2*)&b2[s * 32 + cp * 2];
        float2 o;
        o.x = t2.x * d + bb.x;
        o.y = t2.y * d + bb.y;
        ((float2*)out)[(size_t)node * 32 + s * 16 + cp] = o;
    }
}

extern "C" void kernel_launch(void* const* d_in, const int* in_sizes, int n_in,
                              void* d_out, int out_size, void* d_ws, size_t ws_size,
                              hipStream_t stream) {
    const float* x  = (const float*)d_in[0];
    const int*   ei = (const int*)d_in[1];
    const float* W1 = (const float*)d_in[2];
    const float* b1 = (const float*)d_in[3];
    const float* W2 = (const float*)d_in[4];
    const float* b2 = (const float*)d_in[5];
    float* out = (float*)d_out;

    int n = in_sizes[0] / 128;       // 50000
    int e = in_sizes[1] / 2;         // 800000
    const int* row = ei;             // sources
    const int* col = ei + e;         // destinations

    int nbR = (e + EPB - 1) / EPB;   // 196 pass-1 blocks
    int nbB = (n + 255) / 256;       // 196 buckets
    int m   = nbB * nbR;             // 38416 per-(bucket,block) offsets

    // Workspace layout (int units; 16B-aligned sections).
    int* iw = (int*)d_ws;
    size_t o = 0;
    int* bucket_cnt  = iw + o; o += 256;
    int* bucket_base = iw + o; o += 256;                 // nbB+1 <= 197
    int* bbase       = iw + o; o += (size_t)m;           o = (o + 3) & ~(size_t)3;
    int* indptr      = iw + o; o += (size_t)(n + 1);     o = (o + 3) & ~(size_t)3;
    float* dinv      = (float*)(iw + o); o += (size_t)n; o = (o + 3) & ~(size_t)3;
    unsigned int* tmp = (unsigned int*)(iw + o); o += (size_t)e; o = (o + 3) & ~(size_t)3;
    unsigned short* srcidx = (unsigned short*)(iw + o); o += (size_t)(e / 2 + 2); o = (o + 3) & ~(size_t)3;
    unsigned short* Wt1 = (unsigned short*)(iw + o); o += 8192;
    unsigned short* Wt2 = (unsigned short*)(iw + o); o += 4096;
    unsigned short* hs  = (unsigned short*)(iw + o);     // [4][n][32] bf16
    unsigned short* h1  = hs + (size_t)n * 128;          // [4][n][32] bf16
    unsigned short* ps2 = hs;                            // reuse: [2][n][32]

    k_init<<<1, 256, 0, stream>>>(bucket_cnt);
    k_rhist<<<nbR + 96, 256, 0, stream>>>(col, bbase, bucket_cnt, W1, W2, Wt1, Wt2, e, nbR, nbB);
    k_scanB<<<1, 256, 0, stream>>>(bucket_cnt, bucket_base, nbB);
    k_rscatter<<<nbR, 256, 0, stream>>>(row, col, bucket_base, bbase, tmp, e, nbR, nbB);
    k_bsort<<<nbB, 256, 0, stream>>>(tmp, bucket_base, indptr, dinv, srcidx, n, e, nbB);

    int nbg = (n + 127) / 128;
    int nbn = (n + 3) / 4;           // 12500 blocks per slice (4 waves/block)
    k_gemm1<<<nbg, 256, 0, stream>>>(x, Wt1, dinv, hs, n);
    k_gather1s<<<4 * nbn, 256, 0, stream>>>(indptr, srcidx, hs, dinv, b1, h1, n, nbn);
    k_gemm2<<<nbg, 256, 0, stream>>>(h1, Wt2, dinv, ps2, n);
    k_gather2s<<<2 * nbn, 256, 0, stream>>>(indptr, srcidx, ps2, dinv, b2, out, n, nbn);
}